// Round 6
// baseline (214.485 us; speedup 1.0000x reference)
//
#include <hip/hip_runtime.h>
#include <hip/hip_bf16.h>
#include <stdint.h>

// h [8, 2048, 128] fp32 -> adj = softmax(cos_sim / T) [8, 2048, 2048] fp32
#define NB 8
#define NN 2048
#define ND 128
#define NT 32                       // 16-col tiles per col-quarter (512/16)

typedef __attribute__((ext_vector_type(8))) short short8;   // 8 bf16 (MFMA A/B frag)
typedef __attribute__((ext_vector_type(4))) float f32x4;    // MFMA C/D frag

__device__ __forceinline__ uint32_t pack_bf16(float a, float b) {
    unsigned short ua = __builtin_bit_cast(unsigned short, __float2bfloat16(a));
    unsigned short ub = __builtin_bit_cast(unsigned short, __float2bfloat16(b));
    return (uint32_t)ua | ((uint32_t)ub << 16);
}
__device__ __forceinline__ float unpk_lo(uint32_t p) { return __builtin_bit_cast(float, p << 16); }
__device__ __forceinline__ float unpk_hi(uint32_t p) { return __builtin_bit_cast(float, p & 0xffff0000u); }

// async global->LDS, 16B per lane; LDS dest = wave-uniform base + lane*16
__device__ __forceinline__ void gload_lds16(const void* g, void* l) {
    __builtin_amdgcn_global_load_lds(
        (const __attribute__((address_space(1))) unsigned int*)g,
        (__attribute__((address_space(3))) unsigned int*)l, 16, 0, 0);
}

// Kernel 1: fp32 row-normalize -> bf16 hn in workspace.
__global__ __launch_bounds__(256) void adjnorm_kernel(const float* __restrict__ h,
                                                      unsigned short* __restrict__ hn) {
    const int row  = blockIdx.x * 4 + (threadIdx.x >> 6);
    const int lane = threadIdx.x & 63;
    const float2 v = reinterpret_cast<const float2*>(h + (size_t)row * ND)[lane];
    float ss = v.x * v.x + v.y * v.y;
    #pragma unroll
    for (int m = 32; m >= 1; m >>= 1) ss += __shfl_xor(ss, m);
    const float nrm = fmaxf(sqrtf(ss), 1e-8f);   // torch cosine_similarity eps
    const float inv = 1.0f / nrm;
    reinterpret_cast<uint32_t*>(hn + (size_t)row * ND)[lane] = pack_bf16(v.x * inv, v.y * inv);
}

// Kernel 2: fused sim-GEMM + softmax, m97-style lockstep LDS pipeline.
// Block = 8 waves (2 row-halves rh x 4 col-quarters cq), 32 rows x 2048 cols.
// Per step: rh==0 waves global_load_lds the NEXT 16x128 B-tile (XOR-swizzled via
// pre-swizzled global source), all waves ds_read+MFMA the current one. 1 barrier/step.
// MFMA operands SWAPPED (mfma(b,a)): D col (lane&15) = output row -> each thread
// owns 4 consecutive output cols of one row -> dwordx4 epilogue stores, scalar rowsum.
// Softmax uses constant max 1/T (cos-sim bounded by 1, diag == 1): p = exp((s-1)/T).
__global__ __launch_bounds__(512, 4) void adjmain_kernel(const unsigned short* __restrict__ hn,
                                                         const float* __restrict__ tptr,
                                                         float* __restrict__ out) {
    const int b       = blockIdx.y;
    const int rowBase = blockIdx.x * 32;
    const int lane = threadIdx.x & 63;
    const int wid  = threadIdx.x >> 6;
    const int cq   = wid & 3;        // col quarter [cq*512, +512)
    const int rh   = wid >> 2;       // row half   [rh*16, +16) of the 32-row strip
    const int l15  = lane & 15;
    const int g    = lane >> 4;

    const float invt = 1.0f / tptr[0];
    const unsigned short* Hb = hn + (size_t)b * NN * ND;

    __shared__ char btile[2][4][4096];      // [dbuf][cq][16 rows x 256B], XOR-swizzled
    __shared__ float rsum_lds[2][4][16];

    // A fragments: rows rowBase + rh*16 + l15, K=128 in 4 chunks (frag layout same for a/b operand)
    short8 afrag[4];
    {
        const unsigned short* ap = Hb + (size_t)(rowBase + rh * 16 + l15) * ND + g * 8;
        #pragma unroll
        for (int c = 0; c < 4; ++c)
            afrag[c] = *reinterpret_cast<const short8*>(ap + c * 32);
    }

    // Staging (rh==0 waves, wave cq stages its own slice): LDS is written linearly
    // (base + lane*16); the bank-conflict swizzle is applied by permuting the GLOBAL
    // source so that physical LDS addr P holds logical data L(P) = P ^ (((P>>8)&7)<<4).
    const unsigned short* gsrc[4];
    if (rh == 0) {
        #pragma unroll
        for (int i = 0; i < 4; ++i) {
            const int P = i * 1024 + lane * 16;
            const int L = P ^ (((P >> 8) & 7) << 4);
            gsrc[i] = Hb + (size_t)(cq * 512 + (L >> 8)) * ND + ((L & 255) >> 1);
        }
    }

#define STAGE(T, D) do {                                                \
        char* _lb = &btile[D][cq][0];                                   \
        const size_t _o = (size_t)(T) * 16 * ND;                        \
        gload_lds16(gsrc[0] + _o, _lb);                                 \
        gload_lds16(gsrc[1] + _o, _lb + 1024);                          \
        gload_lds16(gsrc[2] + _o, _lb + 2048);                          \
        gload_lds16(gsrc[3] + _o, _lb + 3072);                          \
    } while (0)

    // Swizzled ds_read offsets (t-invariant): logical = l15*256 + g*16 + c*64
    int rdo[4];
    #pragma unroll
    for (int c = 0; c < 4; ++c) {
        const int Lr = l15 * 256 + g * 16 + c * 64;
        rdo[c] = Lr ^ ((l15 & 7) << 4);
    }

    if (rh == 0) STAGE(0, 0);
    __syncthreads();

    float rs = 0.f;
    uint32_t pp[NT][2];              // bf16-packed p, static indexing only
    #pragma unroll
    for (int t = 0; t < NT; ++t) {
        if (rh == 0 && t + 1 < NT) STAGE(t + 1, (t + 1) & 1);
        const char* tb = &btile[t & 1][cq][0];
        f32x4 acc = {0.f, 0.f, 0.f, 0.f};
        #pragma unroll
        for (int c = 0; c < 4; ++c) {
            const short8 bf = *reinterpret_cast<const short8*>(tb + rdo[c]);
            acc = __builtin_amdgcn_mfma_f32_16x16x32_bf16(bf, afrag[c], acc, 0, 0, 0);
        }
        // swapped operands: D row = g*4+reg = tile-local out COL, D col = l15 = out ROW
        const float p0 = __expf((acc[0] - 1.0f) * invt);
        const float p1 = __expf((acc[1] - 1.0f) * invt);
        const float p2 = __expf((acc[2] - 1.0f) * invt);
        const float p3 = __expf((acc[3] - 1.0f) * invt);
        rs += (p0 + p1) + (p2 + p3);
        pp[t][0] = pack_bf16(p0, p1);
        pp[t][1] = pack_bf16(p2, p3);
        __syncthreads();             // staged tile landed (stager drains vmcnt) + buf reuse safe
    }
#undef STAGE

    // Row sum: per thread rs covers cols {t*16 + g*4 + r} of row l15 -> reduce over g
    rs += __shfl_xor(rs, 16);
    rs += __shfl_xor(rs, 32);
    if (g == 0) rsum_lds[rh][cq][l15] = rs;
    __syncthreads();
    const float inv = 1.0f / (rsum_lds[rh][0][l15] + rsum_lds[rh][1][l15] +
                              rsum_lds[rh][2][l15] + rsum_lds[rh][3][l15]);

    // Epilogue: row = rowBase + rh*16 + l15 (fixed per thread), dwordx4 stores
    float* orow = out + ((size_t)b * NN + rowBase + rh * 16 + l15) * NN + cq * 512 + g * 4;
    #pragma unroll
    for (int t = 0; t < NT; ++t) {
        float4 v = make_float4(unpk_lo(pp[t][0]) * inv, unpk_hi(pp[t][0]) * inv,
                               unpk_lo(pp[t][1]) * inv, unpk_hi(pp[t][1]) * inv);
        *reinterpret_cast<float4*>(orow + t * 16) = v;
    }
}

extern "C" void kernel_launch(void* const* d_in, const int* in_sizes, int n_in,
                              void* d_out, int out_size, void* d_ws, size_t ws_size,
                              hipStream_t stream) {
    const float* h  = (const float*)d_in[0];
    const float* tp = (const float*)d_in[1];
    unsigned short* hn = (unsigned short*)d_ws;     // 8*2048*128*2 = 4 MB of ws
    float* out = (float*)d_out;

    hipLaunchKernelGGL(adjnorm_kernel, dim3(NB * NN / 4), dim3(256), 0, stream, h, hn);
    hipLaunchKernelGGL(adjmain_kernel, dim3(NN / 32, NB), dim3(512), 0, stream, hn, tp, out);
}